// Round 8
// baseline (342.066 us; speedup 1.0000x reference)
//
#include <hip/hip_runtime.h>

#define NT 512
#define NWAVE 8
#define PE 136      // WxT staging pitch (bf16 elems), 272 B rows
#define PW1 88      // W1T staging pitch: 48 rows(j) x 80 cols(h)
#define PH 88       // h0 pitch: 16 rows(t) x 80 cols(h), 176 B stride (<=2-way banks)
#define SMEM_BYTES 30208   // stage: WxT 21760 + W1T 8448 ; loop: h0 8x2816=22528

typedef __attribute__((ext_vector_type(8))) short short8;   // 8 x bf16
typedef __attribute__((ext_vector_type(4))) float f32x4;    // MFMA accumulator

// DPP xor-add over the 16-lane col group: basis {1,2,7,15}
#define DPP_ADD(x, ctrl)                                                    \
  ((x) + __uint_as_float(__builtin_amdgcn_mov_dpp(                          \
             __float_as_uint(x), (ctrl), 0xf, 0xf, true)))

__device__ __forceinline__ unsigned short f2b(float f) {
  unsigned int x = __float_as_uint(f);
  return (unsigned short)((x + 0x7fffu + ((x >> 16) & 1u)) >> 16);
}
__device__ __forceinline__ float b2f(unsigned short u) {
  return __uint_as_float(((unsigned int)u) << 16);
}
__device__ __forceinline__ float sigmoidf(float x) {
  return __builtin_amdgcn_rcpf(1.0f + __expf(-x));
}
__device__ __forceinline__ short8 pack8(float4 a, float4 b) {
  short8 r;
  r[0] = (short)f2b(a.x); r[1] = (short)f2b(a.y); r[2] = (short)f2b(a.z); r[3] = (short)f2b(a.w);
  r[4] = (short)f2b(b.x); r[5] = (short)f2b(b.y); r[6] = (short)f2b(b.z); r[7] = (short)f2b(b.w);
  return r;
}
__device__ __forceinline__ short8 pack8qb(float4 a, float4 b, short8 qp) {
  short8 r;
  r[0] = (short)f2b(a.x * b2f((unsigned short)qp[0]));
  r[1] = (short)f2b(a.y * b2f((unsigned short)qp[1]));
  r[2] = (short)f2b(a.z * b2f((unsigned short)qp[2]));
  r[3] = (short)f2b(a.w * b2f((unsigned short)qp[3]));
  r[4] = (short)f2b(b.x * b2f((unsigned short)qp[4]));
  r[5] = (short)f2b(b.y * b2f((unsigned short)qp[5]));
  r[6] = (short)f2b(b.z * b2f((unsigned short)qp[6]));
  r[7] = (short)f2b(b.w * b2f((unsigned short)qp[7]));
  return r;
}

// ---- precompute C[b][h] = b0[h] + sum_e q[b][e] * (W0a + W0c)[e][h] ----
__global__ __launch_bounds__(256, 2) void prep_c(
    const float* __restrict__ q, const float* __restrict__ W0,
    const float* __restrict__ b0, float* __restrict__ C, int B)
{
  __shared__ float Wac[64 * 80];
  __shared__ float qlds[32 * 64];
  const int bbase = blockIdx.x * 32, tid = threadIdx.x;
  for (int idx = tid; idx < 5120; idx += 256) {
    const int e = idx / 80, h = idx - e * 80;
    Wac[idx] = W0[e * 80 + h] + W0[(128 + e) * 80 + h];
  }
  for (int idx = tid; idx < 2048; idx += 256) {
    const int bl = idx >> 6, e = idx & 63;
    const int bg = bbase + bl;
    qlds[idx] = (bg < B) ? q[bg * 64 + e] : 0.0f;
  }
  __syncthreads();
  #pragma unroll
  for (int i = 0; i < 10; ++i) {
    const int idx = tid + i * 256;
    const int bl = idx / 80, h = idx - bl * 80;
    const int bg = bbase + bl;
    if (bg < B) {
      float acc = b0[h];
      #pragma unroll 8
      for (int e = 0; e < 64; ++e) acc += qlds[bl * 64 + e] * Wac[e * 80 + h];
      C[bg * 80 + h] = acc;
    }
  }
}

// ---- main: 2 waves per batch (even/odd tiles), all weights in registers ----
// 1024 blocks x 8 waves = 8192 waves = 32 waves/CU (4 blocks/CU: LDS 30.2 KB,
// VGPR cap 256 via launch_bounds(512,1) per the session's verified model).
// Prologue: stage WxT/W1T in LDS (coalesced) -> barrier -> load all 29 MFMA
// weight fragments into registers -> barrier -> LDS region is REUSED for the
// per-wave h0 tiles. Per 16-row tile: zero weight ds_reads (regs), h0
// roundtrip is the only LDS traffic (20 wb16 + 3 b128), DPP score reduce,
// in-lane float4 epilogue. Two waves of a batch atomicAdd their halves
// (exactly commutative: 2 contributions) onto a zeroed out buffer.
__global__ __launch_bounds__(NT, 1) void din_attn_main(
    const float* __restrict__ q,
    const float* __restrict__ keys,
    const int* __restrict__ klen,
    const float* __restrict__ W0,
    const float* __restrict__ b0,
    const float* __restrict__ W1,
    const float* __restrict__ b1,
    const float* __restrict__ W2,
    const float* __restrict__ b2,
    float* __restrict__ out,
    const float* __restrict__ Cpre,
    int B)
{
  __shared__ __align__(16) unsigned char smem[SMEM_BYTES];
  unsigned short* WxT = (unsigned short*)smem;             // [80][PE]
  unsigned short* W1T = (unsigned short*)(smem + 21760);   // [48][PW1]

  const int tid = threadIdx.x;

  // ---- stage weights (coalesced global reads, bf16 fold) ----
  for (int idx = tid; idx < 128 * 80; idx += NT) {
    const int e = idx / 80, h = idx - e * 80;
    const float v = (e < 64)
        ? (W0[(64 + e) * 80 + h] - W0[(128 + e) * 80 + h])
        : W0[(128 + e) * 80 + h];
    WxT[h * PE + e] = f2b(v);
  }
  for (int idx = tid; idx < 48 * PW1; idx += NT) {
    const int j = idx / PW1, h = idx - j * PW1;
    W1T[idx] = (j < 40 && h < 80) ? f2b(W1[h * 40 + j]) : (unsigned short)0;
  }
  __syncthreads();

  const int wv = __builtin_amdgcn_readfirstlane(tid >> 6);
  const int lane = tid & 63;
  const int lm = lane & 15;
  const int quad = lane >> 4;
  const short8 z8 = {0, 0, 0, 0, 0, 0, 0, 0};
  const float4 z4 = {0.0f, 0.0f, 0.0f, 0.0f};

  // ---- all weight fragments -> registers (one-time) ----
  short8 wx[5][4];    // layer-1: [nt][kslice]
  #pragma unroll
  for (int nt = 0; nt < 5; ++nt) {
    const unsigned short* wr = &WxT[(nt * 16 + lm) * PE + quad * 8];
    #pragma unroll
    for (int s = 0; s < 4; ++s) wx[nt][s] = *(const short8*)(wr + 32 * s);
  }
  short8 w1f[3][3];   // layer-2: [nt][kslice], kslice 2 masked (K=80)
  #pragma unroll
  for (int nt = 0; nt < 3; ++nt) {
    const unsigned short* wr = &W1T[(nt * 16 + lm) * PW1 + quad * 8];
    w1f[nt][0] = *(const short8*)(wr);
    w1f[nt][1] = *(const short8*)(wr + 32);
    w1f[nt][2] = (quad < 2) ? *(const short8*)(wr + 64) : z8;
  }
  __syncthreads();   // LDS handoff: staging -> h0 region

  unsigned short* h0 = (unsigned short*)smem + wv * (16 * PH);

  const int gw = blockIdx.x * NWAVE + wv;
  const int b = gw >> 1;            // 2 waves per batch
  const int half = gw & 1;          // even/odd 16-row tiles
  if (b >= B) return;

  int L = klen[b];
  L = __builtin_amdgcn_readfirstlane(max(0, min(200, L)));
  const int nu = (L + 15) >> 4;

  // per-batch constants
  const float4* q4 = (const float4*)(q + (size_t)b * 64);
  const short8 qpk0 = pack8(q4[quad * 2], q4[quad * 2 + 1]);
  const short8 qpk1 = pack8(q4[8 + quad * 2], q4[8 + quad * 2 + 1]);

  float cfv[5];
  if (Cpre != nullptr) {
    #pragma unroll
    for (int nt = 0; nt < 5; ++nt) cfv[nt] = Cpre[b * 80 + nt * 16 + lm];
  } else {
    #pragma unroll
    for (int nt = 0; nt < 5; ++nt) cfv[nt] = b0[nt * 16 + lm];
    for (int e = 0; e < 64; ++e) {
      const float qv = q[(size_t)b * 64 + e];
      #pragma unroll
      for (int nt = 0; nt < 5; ++nt) {
        const int col = nt * 16 + lm;
        cfv[nt] += qv * (W0[e * 80 + col] + W0[(128 + e) * 80 + col]);
      }
    }
  }
  float b1v[3], w2v[3];
  #pragma unroll
  for (int nt = 0; nt < 3; ++nt) {
    const int col = nt * 16 + lm;
    b1v[nt] = (col < 40) ? b1[col] : 0.0f;
    w2v[nt] = (col < 40) ? W2[col] : 0.0f;
  }
  const float b2v = b2[0];

  const float* kb = keys + (size_t)b * 12800;
  float4 w4 = {0.0f, 0.0f, 0.0f, 0.0f};

  // prefetch first owned tile (p = half)
  float4 k0 = z4, k1 = z4, k2 = z4, k3 = z4;
  if (half < nu) {
    const int t = (half << 4) + lm;
    if (t < L) {
      const float4* kp = (const float4*)(kb + (size_t)t * 64);
      k0 = kp[quad * 2]; k1 = kp[quad * 2 + 1];
      k2 = kp[8 + quad * 2]; k3 = kp[8 + quad * 2 + 1];
    }
  }

  for (int p = half; p < nu; p += 2) {
    const int t0 = p << 4;

    // ---- pack set0 from prefetched regs ----
    short8 a0 = pack8(k0, k1), a1 = pack8(k2, k3);
    short8 aq0 = pack8qb(k0, k1, qpk0), aq1 = pack8qb(k2, k3, qpk1);
    if (!((t0 + lm) < L)) { a0 = z8; a1 = z8; aq0 = z8; aq1 = z8; }

    // ---- depth-1 prefetch of next owned tile (p+2) ----
    if (p + 2 < nu) {
      const int t = ((p + 2) << 4) + lm;
      if (t < L) {
        const float4* kp = (const float4*)(kb + (size_t)t * 64);
        k0 = kp[quad * 2]; k1 = kp[quad * 2 + 1];
        k2 = kp[8 + quad * 2]; k3 = kp[8 + quad * 2 + 1];
      } else { k0 = z4; k1 = z4; k2 = z4; k3 = z4; }
    }

    // ---- layer 1: h0[16x80] = sigmoid(x[16x128] @ Wx + C), weights in regs ----
    __builtin_amdgcn_s_setprio(1);
    #pragma unroll
    for (int nt = 0; nt < 5; ++nt) {
      const int col = nt * 16 + lm;
      f32x4 acc;
      acc[0] = cfv[nt]; acc[1] = cfv[nt]; acc[2] = cfv[nt]; acc[3] = cfv[nt];
      acc = __builtin_amdgcn_mfma_f32_16x16x32_bf16(a0,  wx[nt][0], acc, 0, 0, 0);
      acc = __builtin_amdgcn_mfma_f32_16x16x32_bf16(a1,  wx[nt][1], acc, 0, 0, 0);
      acc = __builtin_amdgcn_mfma_f32_16x16x32_bf16(aq0, wx[nt][2], acc, 0, 0, 0);
      acc = __builtin_amdgcn_mfma_f32_16x16x32_bf16(aq1, wx[nt][3], acc, 0, 0, 0);
      #pragma unroll
      for (int r = 0; r < 4; ++r)
        h0[(quad * 4 + r) * PH + col] = f2b(sigmoidf(acc[r]));
    }
    __builtin_amdgcn_s_setprio(0);

    // ---- layer 2+3: intra-wave h0 roundtrip (K=80, masked quad) ----
    const short8 ha0 = *(const short8*)&h0[lm * PH + quad * 8];
    const short8 ha1 = *(const short8*)&h0[lm * PH + 32 + quad * 8];
    const short8 ha2 = (quad < 2) ? *(const short8*)&h0[lm * PH + 64 + quad * 8] : z8;
    float pd[4] = {0.0f, 0.0f, 0.0f, 0.0f};
    __builtin_amdgcn_s_setprio(1);
    #pragma unroll
    for (int nt = 0; nt < 3; ++nt) {
      f32x4 acc;
      acc[0] = b1v[nt]; acc[1] = b1v[nt]; acc[2] = b1v[nt]; acc[3] = b1v[nt];
      acc = __builtin_amdgcn_mfma_f32_16x16x32_bf16(ha0, w1f[nt][0], acc, 0, 0, 0);
      acc = __builtin_amdgcn_mfma_f32_16x16x32_bf16(ha1, w1f[nt][1], acc, 0, 0, 0);
      acc = __builtin_amdgcn_mfma_f32_16x16x32_bf16(ha2, w1f[nt][2], acc, 0, 0, 0);
      #pragma unroll
      for (int r = 0; r < 4; ++r) pd[r] += sigmoidf(acc[r]) * w2v[nt];
    }
    __builtin_amdgcn_s_setprio(0);

    // ---- reduce over the 16 col-lanes on the VALU pipe (DPP) ----
    #pragma unroll
    for (int r = 0; r < 4; ++r) {
      pd[r] = DPP_ADD(pd[r], 0xB1);    // xor 1
      pd[r] = DPP_ADD(pd[r], 0x4E);    // xor 2
      pd[r] = DPP_ADD(pd[r], 0x141);   // xor 7
      pd[r] = DPP_ADD(pd[r], 0x140);   // xor 15
    }
    float sc[4];
    #pragma unroll
    for (int r = 0; r < 4; ++r) {
      const int ta = t0 + 4 * quad + r;
      sc[r] = (ta < L) ? sigmoidf(pd[r] + b2v) : 0.0f;
    }

    // ---- epilogue: w4[e=4lm..+3] += sc[r] * keys[t0+4q+r][4lm..+3] ----
    #pragma unroll
    for (int r = 0; r < 4; ++r) {
      const float4 kv = *(const float4*)(kb + (size_t)min(t0 + 4 * quad + r, 199) * 64 + 4 * lm);
      w4.x += sc[r] * kv.x; w4.y += sc[r] * kv.y;
      w4.z += sc[r] * kv.z; w4.w += sc[r] * kv.w;
    }
  }

  // ---- per half-batch: sum the 4 quads, then atomic-combine the 2 halves ----
  w4.x += __shfl_xor(w4.x, 16); w4.y += __shfl_xor(w4.y, 16);
  w4.z += __shfl_xor(w4.z, 16); w4.w += __shfl_xor(w4.w, 16);
  w4.x += __shfl_xor(w4.x, 32); w4.y += __shfl_xor(w4.y, 32);
  w4.z += __shfl_xor(w4.z, 32); w4.w += __shfl_xor(w4.w, 32);
  if (lane < 16) {
    float* op = out + (size_t)b * 64 + 4 * lm;
    atomicAdd(op + 0, w4.x); atomicAdd(op + 1, w4.y);
    atomicAdd(op + 2, w4.z); atomicAdd(op + 3, w4.w);
  }
}

extern "C" void kernel_launch(void* const* d_in, const int* in_sizes, int n_in,
                              void* d_out, int out_size, void* d_ws, size_t ws_size,
                              hipStream_t stream) {
  const int B = in_sizes[2];
  const float* Cpre = nullptr;
  hipMemsetAsync(d_out, 0, (size_t)out_size, stream);
  if (ws_size >= (size_t)B * 80 * sizeof(float)) {
    float* C = (float*)d_ws;
    prep_c<<<(B + 31) / 32, 256, 0, stream>>>(
        (const float*)d_in[0], (const float*)d_in[3], (const float*)d_in[4], C, B);
    Cpre = C;
  }
  const int nwaves = 2 * B;   // 2 waves per batch
  din_attn_main<<<(nwaves + NWAVE - 1) / NWAVE, NT, 0, stream>>>(
      (const float*)d_in[0], (const float*)d_in[1], (const int*)d_in[2],
      (const float*)d_in[3], (const float*)d_in[4], (const float*)d_in[5],
      (const float*)d_in[6], (const float*)d_in[7], (const float*)d_in[8],
      (float*)d_out, Cpre, B);
}